// Round 11
// baseline (315.819 us; speedup 1.0000x reference)
//
#include <hip/hip_runtime.h>
#include <math.h>

#define NB 10
#define PPC 29          // 3*NB-1
#define CCH 4
#define HID 64
#define HH 256
#define WW 256
#define BB 16
#define TB 1.0f
#define MINW 0.001f
#define MINH 0.001f
#define MIND 0.001f

#define ZTOT (BB*CCH*HH*WW)     // 4194304

// R11 tile: 16 wide x 4 tall. M=64 pixels, N=128 (116 valid), K=576.
// Half-size tile -> acc 32 f32/thread -> launch_bounds(256,5) -> 20 waves/CU
// (was 16), and the epilogue is ONE pass (64 pix x 4 ch = 256 threads exactly).
#define TH 4
#define TWD 16
#define HALO_PIX 108            // 6 rows x 18 cols
// LINEAR HSTR=72 (R8's XOR swizzle cost more address-VALU than it saved; the
// residual SQ_LDS_BANK_CONFLICT is b128's inherent 8-access/bank floor).
#define HSTR 72                 // s_hid row stride (bf16): 64 + 8 pad -> rows 16B-aligned (b128 reads)
#define PSTR 117                // p_buf row stride (f32): odd -> conflict-free spline reads
#define NCOLS 116               // valid N columns; >=116 is zero-padding (never stored)
#define W2B_ELEMS (18*8*64*8)   // 73728 bf16, single (hi) copy (R10)

typedef __attribute__((ext_vector_type(8))) short short8v;
typedef __attribute__((ext_vector_type(4))) short short4v;
typedef __attribute__((ext_vector_type(4))) float f32x4;

__device__ inline unsigned short f2bf(float f) {
    unsigned u = __float_as_uint(f);
    unsigned r = (u + 0x7FFFu + ((u >> 16) & 1u)) >> 16;
    return (unsigned short)r;
}

// Prepack W2 -> bf16 fragment order (hi copy ONLY — R10).
// w2b[kidx(18)][ntile(8)][lane(64)][j(8)]
// kidx = tap*2 + ks; n = ntile*16 + (lane&15); ci = ks*32 + (lane>>4)*8 + j
//
// Precision ladder (all verified passed, absmax bit-identical 0.0039):
//   R9: conv2 W2_hi only; R10: conv1 pure bf16 (outputs bf16-quantized anyway).
//
// W1 stuffing in the n>=116 padding (products land in discarded cols):
//   W1 fragment f = ks*4 + nt1, read-lane L, elem j:
//     co = nt1*16 + (L&15); k = ks*32 + (L>>4)*8 + j; v = (k<36) ? W1[co][k&3][k>>2] : 0
//   stored at (kidx = f*2 + (L>>5), nt = 7, slotLane, j),
//     m = L&31, slotLane = (m>>3)*16 + 4 + (m&7)
//
// Block 288 zeroes the 16 logabsdet slots (zero_lad folded in).
__global__ void prepack_w2(const float* __restrict__ W2, const float* __restrict__ W1,
                           unsigned short* __restrict__ w2b, float* __restrict__ out) {
    if (blockIdx.x == (W2B_ELEMS + 255)/256) {
        if (threadIdx.x < 16) out[ZTOT + threadIdx.x] = 0.0f;
        return;
    }
    int idx = blockIdx.x * 256 + threadIdx.x;
    if (idx >= W2B_ELEMS) return;
    int j    = idx & 7;
    int lane = (idx >> 3) & 63;
    int nt   = (idx >> 9) & 7;
    int kidx = idx >> 12;            // 0..17
    int tap  = kidx >> 1;
    int ks   = kidx & 1;
    int ky   = tap / 3;
    int kx   = tap - ky * 3;
    int n    = nt * 16 + (lane & 15);
    int ci   = ks * 32 + (lane >> 4) * 8 + j;
    float v = 0.0f;
    if (n < PPC * CCH) v = W2[((n * HID + ci) * 3 + ky) * 3 + kx];

    // ---- W1 slot? (padding region) ----
    int l15s = lane & 15;
    if (nt == 7 && kidx < 16 && l15s >= 4 && l15s < 12) {
        int f   = kidx >> 1;
        int hi5 = kidx & 1;
        int L   = hi5 * 32 + (lane >> 4) * 8 + (l15s - 4);
        int ks2 = f >> 2;
        int nt1 = f & 3;
        int co  = nt1 * 16 + (L & 15);
        int k   = ks2 * 32 + (L >> 4) * 8 + j;
        v = 0.0f;
        if (k < 36) {
            int tp  = k >> 2;
            int c   = k & 3;
            int ky2 = tp / 3;
            int kx2 = tp - ky2 * 3;
            v = W1[((co * CCH + c) * 3 + ky2) * 3 + kx2];
        }
    }

    w2b[idx] = f2bf(v);
}

__global__ __launch_bounds__(256, 5)
void fused_kernel(const float* __restrict__ x, const float* __restrict__ clean,
                  const float* __restrict__ b1,
                  const float* __restrict__ b2, const unsigned short* __restrict__ w2b,
                  float* __restrict__ out)
{
    // LDS union: one 29952 B region serves all three phase-local buffers.
    //   [0, 15552)      s_hid   (108*HSTR bf16)   live: Phase B write -> Phase C reads
    //   [15552, 16832)  s_cl    (640 bf16)        live: Phase A write -> Phase B reads
    //   [0, 29952)      p_buf   (64*PSTR f32)     live: epilogue only
    // All aliasing is barrier-ordered. 5 blocks/CU: LDS 5*29952=146KB <= 160KB,
    // regs capped at 102/wave by launch_bounds(256,5) (acc is 32 now).
    __shared__ __align__(16) float s_all[64 * PSTR];       // 29952 B
    __shared__ float s_red[4];

    unsigned short* s_hid = (unsigned short*)s_all;                 // 7776 shorts
    unsigned short* s_cl  = (unsigned short*)s_all + 7776;          // 640 shorts (16B-aligned)

    const int tid  = threadIdx.x;
    const int blk  = blockIdx.x;
    const int b    = blk >> 10;
    const int ty   = (blk >> 4) & 63;
    const int tx   = blk & 15;
    const int Y0 = ty * TH, X0 = tx * TWD;

    const int w    = tid >> 6;        // wave id == spline channel c
    const int lane = tid & 63;
    const int l15  = lane & 15;
    const int quad = lane >> 4;
    const int wy   = w & 1;           // M half: mtiles wy*2 .. wy*2+1 (output rows)
    const int wx   = w >> 1;          // N half: ntiles wx*4 .. wx*4+3

    // ---------- Phase A: stage clean tile (8 x 20 x 4ch, zero-padded) as bf16 ----------
    for (int i = tid; i < 640; i += 256) {
        int c  = i / 160;             // plane-major iteration -> coalesced global loads
        int r  = i - c * 160;
        int cy = r / 20;
        int cx = r - cy * 20;
        int iy = Y0 - 2 + cy, ix = X0 - 2 + cx;
        float v = 0.0f;
        if (iy >= 0 && iy < HH && ix >= 0 && ix < WW)
            v = clean[((b*CCH + c) << 16) + iy*WW + ix];
        s_cl[r * 4 + c] = f2bf(v);    // c-contiguous LDS layout for b64 fragment reads
    }
    __syncthreads();

    // ---------- Phase B: hid = relu(conv1(clean)) via MFMA, pure bf16 ----------
    // M = 108 halo pixels (pad 112 -> 7 mtiles, 2/wave), N = 64 (4 ntiles), K = 36 pad 64.
    {
        const short8v* __restrict__ wv = (const short8v*)w2b;
        const int hi5 = lane >> 5;
        const int mm  = lane & 31;
        const int slotLane = ((mm >> 3) << 4) + 4 + (mm & 7);   // inverse of prepack's L decode

        f32x4 acc1[2][4];
        #pragma unroll
        for (int nt = 0; nt < 4; ++nt) {
            float bv = b1[nt*16 + l15];               // C col = l15 -> co
            #pragma unroll
            for (int mt = 0; mt < 2; ++mt) {
                acc1[mt][nt][0] = bv; acc1[mt][nt][1] = bv;
                acc1[mt][nt][2] = bv; acc1[mt][nt][3] = bv;
            }
        }
        // Per-lane tap offsets: quad q covers taps {2q,2q+1} (ks=0) and tap 8 (ks=1; k>=36 zeroed in B).
        int t0 = quad * 2, t1 = quad * 2 + 1;
        int ky0 = t0 / 3, kx0 = t0 - ky0 * 3;
        int ky1 = t1 / 3, kx1 = t1 - ky1 * 3;
        const int o0 = (ky0 * 20 + kx0) * 4;
        const int o1 = (ky1 * 20 + kx1) * 4;
        const int o8 = (2 * 20 + 2) * 4;              // tap 8 -> (ky,kx)=(2,2)

        #pragma unroll
        for (int ks = 0; ks < 2; ++ks) {
            const int oA = ks ? o8 : o0;
            const int oB = ks ? o8 : o1;
            short8v ah[2];
            #pragma unroll
            for (int mt = 0; mt < 2; ++mt) {
                int p  = (w*2 + mt)*16 + l15;          // A row = halo pixel
                int pc = p > HALO_PIX-1 ? HALO_PIX-1 : p;   // clamp pad rows (results discarded)
                int hy = pc / 18, hx = pc - hy * 18;
                int base = (hy * 20 + hx) * 4;
                short4v h0 = *(const short4v*)(s_cl + base + oA);
                short4v h1 = *(const short4v*)(s_cl + base + oB);
                ah[mt] = __builtin_shufflevector(h0, h1, 0,1,2,3,4,5,6,7);
            }
            #pragma unroll
            for (int nt = 0; nt < 4; ++nt) {
                int i8 = (((ks*4 + nt)*2 + hi5)*8 + 7)*64 + slotLane;  // (kidx, nt=7, slotLane)
                short8v bh = wv[i8];
                #pragma unroll
                for (int mt = 0; mt < 2; ++mt)
                    acc1[mt][nt] = __builtin_amdgcn_mfma_f32_16x16x32_bf16(ah[mt], bh, acc1[mt][nt], 0,0,0);
            }
        }
        // Write s_hid bf16. Out-of-image halo pixels must be ZERO (conv2 SAME padding), not relu(b1).
        #pragma unroll
        for (int mt = 0; mt < 2; ++mt) {
            #pragma unroll
            for (int r = 0; r < 4; ++r) {
                int p = (w*2 + mt)*16 + quad*4 + r;    // C row = quad*4 + reg
                if (p < HALO_PIX) {
                    int hy = p / 18, hx = p - hy * 18;
                    int iy = Y0 - 1 + hy, ix = X0 - 1 + hx;
                    bool valid = (iy >= 0 && iy < HH && ix >= 0 && ix < WW);
                    #pragma unroll
                    for (int nt = 0; nt < 4; ++nt) {
                        float v = valid ? fmaxf(acc1[mt][nt][r], 0.0f) : 0.0f;
                        s_hid[p*HSTR + nt*16 + l15] = f2bf(v);
                    }
                }
            }
        }
    }
    __syncthreads();

    // ---------- x prefetch: this thread's spline input, issued before Phase C ----------
    const int gbase = ((b*CCH + w) << 16) + (Y0 + quad)*WW + X0 + l15;
    float xv = x[gbase];

    // ---------- Phase C: conv2 as implicit GEMM via MFMA 16x16x32 (W2_hi) ----------
    // Wave (wy,wx): 2 mtiles x 4 ntiles = 8 acc tiles (32 f32/thread) -> 8
    // independent MFMA chains. 144 MFMA/wave.
    f32x4 acc[2][4];
    #pragma unroll
    for (int mi = 0; mi < 2; ++mi)
        #pragma unroll
        for (int t = 0; t < 4; ++t) {
            acc[mi][t][0] = 0.f; acc[mi][t][1] = 0.f;
            acc[mi][t][2] = 0.f; acc[mi][t][3] = 0.f;
        }

    const short8v* __restrict__ wbv_hi = (const short8v*)w2b;
    // A addr (shorts): ((wy*2+mi+ky)*18 + l15+kx)*HSTR + quad*8 + ks*32  (16B-aligned -> b128)
    const int abase = (wy*2) * (18*HSTR) + l15*HSTR + quad*8;

    for (int tap = 0; tap < 9; ++tap) {
        int ky = tap / 3;
        int kx = tap - ky * 3;
        int roff = abase + ky*(18*HSTR) + kx*HSTR;
        #pragma unroll
        for (int ks = 0; ks < 2; ++ks) {
            int boff = ((tap*2 + ks)*8 + wx*4)*64 + lane;
            short8v afr[2];
            #pragma unroll
            for (int mi = 0; mi < 2; ++mi)
                afr[mi] = *(const short8v*)(s_hid + roff + mi*(18*HSTR) + ks*32);
            short8v bfr[4];
            #pragma unroll
            for (int t = 0; t < 4; ++t)
                bfr[t] = wbv_hi[boff + t*64];
            __builtin_amdgcn_s_setprio(1);
            #pragma unroll
            for (int mi = 0; mi < 2; ++mi)
                #pragma unroll
                for (int t = 0; t < 4; ++t)
                    acc[mi][t] = __builtin_amdgcn_mfma_f32_16x16x32_bf16(
                        afr[mi], bfr[t], acc[mi][t], 0, 0, 0);
            __builtin_amdgcn_s_setprio(0);
        }
    }

    // ---------- Epilogue: ONE pass — every wave writes its tiles, then 256 threads spline ----------
    float* p_buf = s_all;
    const float* b2c = b2 + w * PPC;      // wave-uniform -> scalar loads
    float lad = 0.0f;

    __syncthreads();   // all s_hid/s_cl reads done before p_buf overwrite
    #pragma unroll
    for (int mi = 0; mi < 2; ++mi) {
        #pragma unroll
        for (int t = 0; t < 4; ++t) {
            int col = (wx*4 + t)*16 + l15;
            if (col < NCOLS) {    // cols >=116 are padding; would wrap PSTR
                f32x4 v = acc[mi][t];
                int base = ((wy*2 + mi)*16 + quad*4) * PSTR + col;
                p_buf[base]          = v[0];
                p_buf[base + PSTR]   = v[1];
                p_buf[base + 2*PSTR] = v[2];
                p_buf[base + 3*PSTR] = v[3];
            }
        }
    }
    __syncthreads();

    // spline: thread -> (c = w, pixel = lane); 64 pix x 4 ch = 256 threads exactly
    {
        float xin = fminf(fmaxf(xv, -TB), TB);
        int gidx  = gbase;

        const int pbase = lane * PSTR + w * PPC;
        const float scale = 0.125f;   // 1/sqrt(HIDDEN)

        // ---- widths softmax (no max-subtract; u bounded, overflow impossible) ----
        float uw[NB];
        float sw = 0.0f;
        #pragma unroll
        for (int j = 0; j < NB; ++j) {
            uw[j] = __expf((p_buf[pbase + j] + b2c[j]) * scale);
            sw += uw[j];
        }
        float isw = 1.0f / sw;

        // cumsum fused with bin locate: last j with xin >= cw[j] gives idx
        float icw = -TB, inw = TB;
        int idx = 0;
        float run = 0.0f;
        float cprev = -TB;
        #pragma unroll
        for (int j = 0; j < NB; ++j) {
            float wj = MINW + (1.0f - MINW*NB) * (uw[j] * isw);
            run += wj;
            float cnext = (j == NB-1) ? TB : (-TB + 2.0f*TB*run);   // cw[j+1]
            bool m = (xin >= cprev);
            icw = m ? cprev : icw;
            inw = m ? cnext : inw;
            idx = m ? j     : idx;
            cprev = cnext;
        }

        // ---- heights softmax, ich/inh selected during cumsum ----
        float uh[NB];
        float sh = 0.0f;
        #pragma unroll
        for (int j = 0; j < NB; ++j) {
            uh[j] = __expf((p_buf[pbase + NB + j] + b2c[NB + j]) * scale);
            sh += uh[j];
        }
        float ish = 1.0f / sh;
        float ich = -TB, inh = -TB;
        float runh = 0.0f;
        #pragma unroll
        for (int j = 0; j < NB; ++j) {
            float c0 = -TB + 2.0f*TB*runh;            // chh[j]
            float hj = MINH + (1.0f - MINH*NB) * (uh[j] * ish);
            runh += hj;
            float c1 = (j == NB-1) ? TB : (-TB + 2.0f*TB*runh);  // chh[j+1]
            bool m = (idx == j);
            ich = m ? c0 : ich;
            inh = m ? c1 : inh;
        }

        // ---- derivatives: only d0 = dv[idx], d1 = dv[idx+1] (2 softplus, not 9) ----
        int k0c = idx - 1; k0c = k0c < 0 ? 0 : k0c;
        int k1c = idx > NB-2 ? NB-2 : idx;
        float u0 = p_buf[pbase + 2*NB + k0c] + b2c[2*NB + k0c];
        float u1 = p_buf[pbase + 2*NB + k1c] + b2c[2*NB + k1c];
        float sp0 = fmaxf(u0, 0.0f) + __logf(1.0f + __expf(-fabsf(u0)));
        float sp1 = fmaxf(u1, 0.0f) + __logf(1.0f + __expf(-fabsf(u1)));
        float d0 = (idx == 0)    ? 1.0f : (MIND + sp0);
        float d1 = (idx == NB-1) ? 1.0f : (MIND + sp1);

        float ibw = inw - icw;
        float ihh = inh - ich;
        float idl = ihh / ibw;
        float th  = (xin - icw) / ibw;
        float omt = 1.0f - th;
        float tt  = th * omt;
        float numer = ihh * (idl*th*th + d0*tt);
        float den   = idl + (d0 + d1 - 2.0f*idl)*tt;
        float z_in  = ich + numer/den;
        float dnum  = idl*idl*(d1*th*th + 2.0f*idl*tt + d0*omt*omt);
        float lad_in = __logf(dnum) - 2.0f*__logf(den);
        bool inside = (xv >= -TB) && (xv <= TB);
        float z = inside ? z_in : xv;
        if (inside) lad = lad_in;
        out[gidx] = z;
    }

    // ---------- block-reduce lad, one atomic per block ----------
    #pragma unroll
    for (int off = 32; off >= 1; off >>= 1)
        lad += __shfl_xor(lad, off, 64);
    if (lane == 0) s_red[w] = lad;
    __syncthreads();
    if (tid == 0)
        atomicAdd(out + ZTOT + b, s_red[0] + s_red[1] + s_red[2] + s_red[3]);
}

extern "C" void kernel_launch(void* const* d_in, const int* in_sizes, int n_in,
                              void* d_out, int out_size, void* d_ws, size_t ws_size,
                              hipStream_t stream) {
    const float* x     = (const float*)d_in[0];
    const float* clean = (const float*)d_in[1];
    const float* W1    = (const float*)d_in[2];
    const float* b1    = (const float*)d_in[3];
    const float* W2    = (const float*)d_in[4];
    const float* b2    = (const float*)d_in[5];
    float* out = (float*)d_out;
    unsigned short* w2b = (unsigned short*)d_ws;   // 147456 B (hi copy only)

    // zero_lad folded into prepack (extra block) -> 2 launches.
    prepack_w2<<<(W2B_ELEMS + 255)/256 + 1, 256, 0, stream>>>(W2, W1, w2b, out);
    fused_kernel<<<BB*64*16, 256, 0, stream>>>(x, clean, b1, b2, w2b, out);
}

// Round 13
// 265.058 us; speedup vs baseline: 1.1915x; 1.1915x over previous
//
#include <hip/hip_runtime.h>
#include <math.h>

#define NB 10
#define PPC 29          // 3*NB-1
#define CCH 4
#define HID 64
#define HH 256
#define WW 256
#define BB 16
#define TB 1.0f
#define MINW 0.001f
#define MINH 0.001f
#define MIND 0.001f

#define ZTOT (BB*CCH*HH*WW)     // 4194304

// Tile: 16 wide x 8 tall. M=128 pixels, N=128 (116 valid), K=576.  (R10 tile —
// R11's half-tile raised occupancy 41->53% but ADDED per-pixel VALU work: 258us.)
#define TH 8
#define TWD 16
#define HALO_PIX 180            // 10 rows x 18 cols
// LINEAR HSTR=72 (R8's XOR swizzle cost more address-VALU than it saved; the
// residual SQ_LDS_BANK_CONFLICT is b128's inherent 8-access/bank floor).
#define HSTR 72                 // s_hid row stride (bf16): 64 + 8 pad -> rows 16B-aligned (b128 reads)
#define PSTR 117                // p_buf row stride (f32): odd -> conflict-free spline reads
#define NCOLS 116               // valid N columns; >=116 is zero-padding (never stored)
#define W2B_ELEMS (18*8*64*8)   // 73728 bf16, single (hi) copy (R10)

typedef __attribute__((ext_vector_type(8))) short short8v;
typedef __attribute__((ext_vector_type(4))) short short4v;
typedef __attribute__((ext_vector_type(4))) float f32x4;

__device__ inline unsigned short f2bf(float f) {
    unsigned u = __float_as_uint(f);
    unsigned r = (u + 0x7FFFu + ((u >> 16) & 1u)) >> 16;
    return (unsigned short)r;
}

// Prepack W2 -> bf16 fragment order (hi copy ONLY — R10).
// w2b[kidx(18)][ntile(8)][lane(64)][j(8)]
// kidx = tap*2 + ks; n = ntile*16 + (lane&15); ci = ks*32 + (lane>>4)*8 + j
//
// Precision ladder (all verified passed, absmax bit-identical 0.0039):
//   R9: conv2 W2_hi only; R10: conv1 pure bf16 (outputs bf16-quantized anyway).
//
// W1 stuffing in the n>=116 padding (products land in discarded cols):
//   W1 fragment f = ks*4 + nt1, read-lane L, elem j:
//     co = nt1*16 + (L&15); k = ks*32 + (L>>4)*8 + j; v = (k<36) ? W1[co][k&3][k>>2] : 0
//   stored at (kidx = f*2 + (L>>5), nt = 7, slotLane, j),
//     m = L&31, slotLane = (m>>3)*16 + 4 + (m&7)
//
// Block 288 zeroes the 16 logabsdet slots (zero_lad folded in).
__global__ void prepack_w2(const float* __restrict__ W2, const float* __restrict__ W1,
                           unsigned short* __restrict__ w2b, float* __restrict__ out) {
    if (blockIdx.x == (W2B_ELEMS + 255)/256) {
        if (threadIdx.x < 16) out[ZTOT + threadIdx.x] = 0.0f;
        return;
    }
    int idx = blockIdx.x * 256 + threadIdx.x;
    if (idx >= W2B_ELEMS) return;
    int j    = idx & 7;
    int lane = (idx >> 3) & 63;
    int nt   = (idx >> 9) & 7;
    int kidx = idx >> 12;            // 0..17
    int tap  = kidx >> 1;
    int ks   = kidx & 1;
    int ky   = tap / 3;
    int kx   = tap - ky * 3;
    int n    = nt * 16 + (lane & 15);
    int ci   = ks * 32 + (lane >> 4) * 8 + j;
    float v = 0.0f;
    if (n < PPC * CCH) v = W2[((n * HID + ci) * 3 + ky) * 3 + kx];

    // ---- W1 slot? (padding region) ----
    int l15s = lane & 15;
    if (nt == 7 && kidx < 16 && l15s >= 4 && l15s < 12) {
        int f   = kidx >> 1;
        int hi5 = kidx & 1;
        int L   = hi5 * 32 + (lane >> 4) * 8 + (l15s - 4);
        int ks2 = f >> 2;
        int nt1 = f & 3;
        int co  = nt1 * 16 + (L & 15);
        int k   = ks2 * 32 + (L >> 4) * 8 + j;
        v = 0.0f;
        if (k < 36) {
            int tp  = k >> 2;
            int c   = k & 3;
            int ky2 = tp / 3;
            int kx2 = tp - ky2 * 3;
            v = W1[((co * CCH + c) * 3 + ky2) * 3 + kx2];
        }
    }

    w2b[idx] = f2bf(v);
}

__global__ __launch_bounds__(256, 4)
void fused_kernel(const float* __restrict__ x, const float* __restrict__ clean,
                  const float* __restrict__ b1,
                  const float* __restrict__ b2, const unsigned short* __restrict__ w2b,
                  float* __restrict__ out)
{
    // LDS union: one 29952 B region serves all three phase-local buffers.
    //   [0, 25920)      s_hid   (180*HSTR bf16)   live: Phase B write -> Phase C reads
    //   [25920, 27840)  s_cl    (960 bf16)        live: Phase A write -> Phase B reads
    //   [0, 29952)      p_buf   (64*PSTR f32)     live: epilogue only
    // All aliasing is barrier-ordered. Regs bind occupancy at 4 wg/CU (R5).
    __shared__ __align__(16) float s_all[64 * PSTR];       // 29952 B
    __shared__ float s_red[4];

    unsigned short* s_hid = (unsigned short*)s_all;                 // 12960 shorts
    unsigned short* s_cl  = (unsigned short*)s_all + 12960;         // 960 shorts (8B-aligned)

    const int tid  = threadIdx.x;
    const int blk  = blockIdx.x;
    const int b    = blk >> 9;
    const int ty   = (blk >> 4) & 31;
    const int tx   = blk & 15;
    const int Y0 = ty * TH, X0 = tx * TWD;

    const int w    = tid >> 6;        // wave id == spline channel c
    const int lane = tid & 63;
    const int l15  = lane & 15;
    const int quad = lane >> 4;
    const int wy   = w & 1;           // M half: mtiles wy*4 .. wy*4+3 (pixel rows)
    const int wx   = w >> 1;          // N half: ntiles wx*4 .. wx*4+3

    // ---------- Phase A: stage clean tile (12 x 20 x 4ch, zero-padded) as bf16 ----------
    for (int i = tid; i < 960; i += 256) {
        int c  = i / 240;             // plane-major iteration -> coalesced global loads
        int r  = i - c * 240;
        int cy = r / 20;
        int cx = r - cy * 20;
        int iy = Y0 - 2 + cy, ix = X0 - 2 + cx;
        float v = 0.0f;
        if (iy >= 0 && iy < HH && ix >= 0 && ix < WW)
            v = clean[((b*CCH + c) << 16) + iy*WW + ix];
        s_cl[r * 4 + c] = f2bf(v);    // c-contiguous LDS layout for b64 fragment reads
    }
    __syncthreads();

    // ---------- Phase B: hid = relu(conv1(clean)) via MFMA, pure bf16 ----------
    // M = 180 halo pixels (pad 192 -> 12 mtiles, 3/wave), N = 64 (4 ntiles), K = 36 pad 64.
    {
        const short8v* __restrict__ wv = (const short8v*)w2b;
        const int hi5 = lane >> 5;
        const int mm  = lane & 31;
        const int slotLane = ((mm >> 3) << 4) + 4 + (mm & 7);   // inverse of prepack's L decode

        f32x4 acc1[3][4];
        #pragma unroll
        for (int nt = 0; nt < 4; ++nt) {
            float bv = b1[nt*16 + l15];               // C col = l15 -> co
            #pragma unroll
            for (int mt = 0; mt < 3; ++mt) {
                acc1[mt][nt][0] = bv; acc1[mt][nt][1] = bv;
                acc1[mt][nt][2] = bv; acc1[mt][nt][3] = bv;
            }
        }
        // Per-lane tap offsets: quad q covers taps {2q,2q+1} (ks=0) and tap 8 (ks=1; k>=36 zeroed in B).
        int t0 = quad * 2, t1 = quad * 2 + 1;
        int ky0 = t0 / 3, kx0 = t0 - ky0 * 3;
        int ky1 = t1 / 3, kx1 = t1 - ky1 * 3;
        const int o0 = (ky0 * 20 + kx0) * 4;
        const int o1 = (ky1 * 20 + kx1) * 4;
        const int o8 = (2 * 20 + 2) * 4;              // tap 8 -> (ky,kx)=(2,2)

        #pragma unroll
        for (int ks = 0; ks < 2; ++ks) {
            const int oA = ks ? o8 : o0;
            const int oB = ks ? o8 : o1;
            short8v ah[3];
            #pragma unroll
            for (int mt = 0; mt < 3; ++mt) {
                int p  = (w*3 + mt)*16 + l15;          // A row = halo pixel
                int pc = p > HALO_PIX-1 ? HALO_PIX-1 : p;   // clamp pad rows (results discarded)
                int hy = pc / 18, hx = pc - hy * 18;
                int base = (hy * 20 + hx) * 4;
                short4v h0 = *(const short4v*)(s_cl + base + oA);
                short4v h1 = *(const short4v*)(s_cl + base + oB);
                ah[mt] = __builtin_shufflevector(h0, h1, 0,1,2,3,4,5,6,7);
            }
            #pragma unroll
            for (int nt = 0; nt < 4; ++nt) {
                int i8 = (((ks*4 + nt)*2 + hi5)*8 + 7)*64 + slotLane;  // (kidx, nt=7, slotLane)
                short8v bh = wv[i8];
                #pragma unroll
                for (int mt = 0; mt < 3; ++mt)
                    acc1[mt][nt] = __builtin_amdgcn_mfma_f32_16x16x32_bf16(ah[mt], bh, acc1[mt][nt], 0,0,0);
            }
        }
        // Write s_hid bf16. Out-of-image halo pixels must be ZERO (conv2 SAME padding), not relu(b1).
        #pragma unroll
        for (int mt = 0; mt < 3; ++mt) {
            #pragma unroll
            for (int r = 0; r < 4; ++r) {
                int p = (w*3 + mt)*16 + quad*4 + r;    // C row = quad*4 + reg
                if (p < HALO_PIX) {
                    int hy = p / 18, hx = p - hy * 18;
                    int iy = Y0 - 1 + hy, ix = X0 - 1 + hx;
                    bool valid = (iy >= 0 && iy < HH && ix >= 0 && ix < WW);
                    #pragma unroll
                    for (int nt = 0; nt < 4; ++nt) {
                        float v = valid ? fmaxf(acc1[mt][nt][r], 0.0f) : 0.0f;
                        s_hid[p*HSTR + nt*16 + l15] = f2bf(v);
                    }
                }
            }
        }
    }
    __syncthreads();

    // ---------- x prefetch: both chunks' inputs issued before Phase C ----------
    const int gbase = ((b*CCH + w) << 16) + (Y0 + quad)*WW + X0 + l15;
    float xv0 = x[gbase];
    float xv1 = x[gbase + 4*WW];

    // ---------- Phase C: conv2 as implicit GEMM via MFMA 16x16x32 (W2_hi) ----------
    // Wave (wy,wx): 4 mtiles x 4 ntiles = 16 acc tiles (64 f32/thread) -> 16
    // independent MFMA chains. 288 MFMA/wave.
    // R12: tap loop fully unrolled — kills the /3 magic-div + roff/boff VALU per
    // iteration, folds all ds_read/global offsets to immediates, and lets the
    // compiler hoist B-fragment loads across taps (software pipelining).
    f32x4 acc[4][4];
    #pragma unroll
    for (int mi = 0; mi < 4; ++mi)
        #pragma unroll
        for (int t = 0; t < 4; ++t) {
            acc[mi][t][0] = 0.f; acc[mi][t][1] = 0.f;
            acc[mi][t][2] = 0.f; acc[mi][t][3] = 0.f;
        }

    const short8v* __restrict__ wbv_hi = (const short8v*)w2b;
    // A addr (shorts): ((wy*4+mi+ky)*18 + l15+kx)*HSTR + quad*8 + ks*32  (16B-aligned -> b128)
    const int abase = (wy*4) * (18*HSTR) + l15*HSTR + quad*8;

    #pragma unroll
    for (int tap = 0; tap < 9; ++tap) {
        const int ky = tap / 3;              // compile-time now
        const int kx = tap - ky * 3;
        const int roff = ky*(18*HSTR) + kx*HSTR;
        #pragma unroll
        for (int ks = 0; ks < 2; ++ks) {
            int boff = ((tap*2 + ks)*8 + wx*4)*64 + lane;
            short8v afr[4];
            #pragma unroll
            for (int mi = 0; mi < 4; ++mi)
                afr[mi] = *(const short8v*)(s_hid + abase + roff + mi*(18*HSTR) + ks*32);
            short8v bfr[4];
            #pragma unroll
            for (int t = 0; t < 4; ++t)
                bfr[t] = wbv_hi[boff + t*64];
            __builtin_amdgcn_s_setprio(1);
            #pragma unroll
            for (int mi = 0; mi < 4; ++mi)
                #pragma unroll
                for (int t = 0; t < 4; ++t)
                    acc[mi][t] = __builtin_amdgcn_mfma_f32_16x16x32_bf16(
                        afr[mi], bfr[t], acc[mi][t], 0, 0, 0);
            __builtin_amdgcn_s_setprio(0);
        }
    }

    // ---------- Epilogue: 2 chunks of 64 pixels through LDS p_buf, then spline ----------
    // R5: cumsum+bin-search+select fused; 2 softplus only. R8: no max-subtract.
    // R12: softmax exps via exp2f with folded scale*log2e constant (one mul per
    // exp instead of two); lad accumulated in log2 domain, scaled by ln2 once.
    float* p_buf = s_all;
    const float* b2c = b2 + w * PPC;      // wave-uniform -> scalar loads
    float lad2 = 0.0f;                    // log2-domain accumulator
    const float C2 = 0.18033688011112042f;   // 0.125 * log2(e)

    for (int chunk = 0; chunk < 2; ++chunk) {
        __syncthreads();   // chunk 0: all s_hid/s_cl reads done; chunk 1: chunk-0 spline reads done
        if (wy == chunk) {
            #pragma unroll
            for (int mi = 0; mi < 4; ++mi) {
                #pragma unroll
                for (int t = 0; t < 4; ++t) {
                    int col = (wx*4 + t)*16 + l15;
                    if (col < NCOLS) {    // cols >=116 are padding; would wrap PSTR
                        f32x4 v = acc[mi][t];
                        int base = (mi*16 + quad*4) * PSTR + col;
                        p_buf[base]          = v[0];
                        p_buf[base + PSTR]   = v[1];
                        p_buf[base + 2*PSTR] = v[2];
                        p_buf[base + 3*PSTR] = v[3];
                    }
                }
            }
        }
        __syncthreads();

        // spline: thread -> (c = w, chunk-local pixel = lane)
        float xv  = chunk ? xv1 : xv0;    // prefetched before Phase C
        float xin = fminf(fmaxf(xv, -TB), TB);
        int gidx  = gbase + chunk*4*WW;

        const int pbase = lane * PSTR + w * PPC;

        // ---- widths softmax (no max-subtract); cumsum fused with bin locate ----
        float uw[NB];
        float sw = 0.0f;
        #pragma unroll
        for (int j = 0; j < NB; ++j) {
            uw[j] = exp2f((p_buf[pbase + j] + b2c[j]) * C2);
            sw += uw[j];
        }
        float isw = 1.0f / sw;

        // last j with xin >= cw[j] gives idx (xin >= -TB always -> j=0 triggers)
        float icw = -TB, inw = TB;
        int idx = 0;
        float run = 0.0f;
        float cprev = -TB;
        #pragma unroll
        for (int j = 0; j < NB; ++j) {
            float wj = MINW + (1.0f - MINW*NB) * (uw[j] * isw);
            run += wj;
            float cnext = (j == NB-1) ? TB : (-TB + 2.0f*TB*run);   // cw[j+1]
            bool m = (xin >= cprev);
            icw = m ? cprev : icw;
            inw = m ? cnext : inw;
            idx = m ? j     : idx;
            cprev = cnext;
        }

        // ---- heights softmax (no max-subtract), ich/inh selected during cumsum ----
        float uh[NB];
        float sh = 0.0f;
        #pragma unroll
        for (int j = 0; j < NB; ++j) {
            uh[j] = exp2f((p_buf[pbase + NB + j] + b2c[NB + j]) * C2);
            sh += uh[j];
        }
        float ish = 1.0f / sh;
        float ich = -TB, inh = -TB;
        float runh = 0.0f;
        #pragma unroll
        for (int j = 0; j < NB; ++j) {
            float c0 = -TB + 2.0f*TB*runh;            // chh[j]
            float hj = MINH + (1.0f - MINH*NB) * (uh[j] * ish);
            runh += hj;
            float c1 = (j == NB-1) ? TB : (-TB + 2.0f*TB*runh);  // chh[j+1]
            bool m = (idx == j);
            ich = m ? c0 : ich;
            inh = m ? c1 : inh;
        }

        // ---- derivatives: only d0 = dv[idx], d1 = dv[idx+1] (2 softplus, not 9) ----
        int k0c = idx - 1; k0c = k0c < 0 ? 0 : k0c;
        int k1c = idx > NB-2 ? NB-2 : idx;
        float u0 = p_buf[pbase + 2*NB + k0c] + b2c[2*NB + k0c];
        float u1 = p_buf[pbase + 2*NB + k1c] + b2c[2*NB + k1c];
        float sp0 = fmaxf(u0, 0.0f) + __logf(1.0f + __expf(-fabsf(u0)));
        float sp1 = fmaxf(u1, 0.0f) + __logf(1.0f + __expf(-fabsf(u1)));
        float d0 = (idx == 0)    ? 1.0f : (MIND + sp0);
        float d1 = (idx == NB-1) ? 1.0f : (MIND + sp1);

        float ibw = inw - icw;
        float ihh = inh - ich;
        float idl = ihh / ibw;
        float th  = (xin - icw) / ibw;
        float omt = 1.0f - th;
        float tt  = th * omt;
        float numer = ihh * (idl*th*th + d0*tt);
        float den   = idl + (d0 + d1 - 2.0f*idl)*tt;
        float z_in  = ich + numer/den;
        float dnum  = idl*idl*(d1*th*th + 2.0f*idl*tt + d0*omt*omt);
        float lad_in2 = log2f(dnum) - 2.0f*log2f(den);   // log2-domain
        bool inside = (xv >= -TB) && (xv <= TB);
        float z = inside ? z_in : xv;
        if (inside) lad2 += lad_in2;
        out[gidx] = z;
    }

    // ---------- block-reduce lad (scale log2->ln once), one atomic per block ----------
    float lad = lad2 * 0.6931471805599453f;
    #pragma unroll
    for (int off = 32; off >= 1; off >>= 1)
        lad += __shfl_xor(lad, off, 64);
    if (lane == 0) s_red[w] = lad;
    __syncthreads();
    if (tid == 0)
        atomicAdd(out + ZTOT + b, s_red[0] + s_red[1] + s_red[2] + s_red[3]);
}

extern "C" void kernel_launch(void* const* d_in, const int* in_sizes, int n_in,
                              void* d_out, int out_size, void* d_ws, size_t ws_size,
                              hipStream_t stream) {
    const float* x     = (const float*)d_in[0];
    const float* clean = (const float*)d_in[1];
    const float* W1    = (const float*)d_in[2];
    const float* b1    = (const float*)d_in[3];
    const float* W2    = (const float*)d_in[4];
    const float* b2    = (const float*)d_in[5];
    float* out = (float*)d_out;
    unsigned short* w2b = (unsigned short*)d_ws;   // 147456 B (hi copy only)

    // zero_lad folded into prepack (extra block) -> 2 launches.
    prepack_w2<<<(W2B_ELEMS + 255)/256 + 1, 256, 0, stream>>>(W2, W1, w2b, out);
    fused_kernel<<<BB*32*16, 256, 0, stream>>>(x, clean, b1, b2, w2b, out);
}

// Round 14
// 262.018 us; speedup vs baseline: 1.2053x; 1.0116x over previous
//
#include <hip/hip_runtime.h>
#include <math.h>

#define NB 10
#define PPC 29          // 3*NB-1
#define CCH 4
#define HID 64
#define HH 256
#define WW 256
#define BB 16
#define TB 1.0f
#define MINW 0.001f
#define MINH 0.001f
#define MIND 0.001f

#define ZTOT (BB*CCH*HH*WW)     // 4194304

// Tile: 16 wide x 8 tall. M=128 pixels, N=128 (116 valid), K=576.
#define TH 8
#define TWD 16
#define HALO_PIX 180            // 10 rows x 18 cols
#define HSTR 72                 // s_hid row stride (bf16): 64 + 8 pad -> rows 16B-aligned (b128 reads)
#define PSTR 117                // p_buf row stride (f32): odd -> conflict-free spline reads
#define NCOLS 116               // valid N columns; >=116 is zero-padding (never stored)
#define W2B_ELEMS (18*8*64*8)   // 73728 bf16, single (hi) copy (R10)

typedef __attribute__((ext_vector_type(8))) short short8v;
typedef __attribute__((ext_vector_type(4))) short short4v;
typedef __attribute__((ext_vector_type(4))) float f32x4;

__device__ inline unsigned short f2bf(float f) {
    unsigned u = __float_as_uint(f);
    unsigned r = (u + 0x7FFFu + ((u >> 16) & 1u)) >> 16;
    return (unsigned short)r;
}

// Prepack W2 -> bf16 fragment order (hi copy ONLY — R10).
// w2b[kidx(18)][ntile(8)][lane(64)][j(8)]
// kidx = tap*2 + ks; n = ntile*16 + (lane&15); ci = ks*32 + (lane>>4)*8 + j
//
// Precision ladder (all verified passed, absmax bit-identical 0.0039):
//   R9: conv2 W2_hi only; R10: conv1 pure bf16 (outputs bf16-quantized anyway).
//
// W1 stuffing in the n>=116 padding (products land in discarded cols):
//   W1 fragment f = ks*4 + nt1, read-lane L, elem j:
//     co = nt1*16 + (L&15); k = ks*32 + (L>>4)*8 + j; v = (k<36) ? W1[co][k&3][k>>2] : 0
//   stored at (kidx = f*2 + (L>>5), nt = 7, slotLane, j),
//     m = L&31, slotLane = (m>>3)*16 + 4 + (m&7)
//
// Block 288 zeroes the 16 logabsdet slots (zero_lad folded in).
__global__ void prepack_w2(const float* __restrict__ W2, const float* __restrict__ W1,
                           unsigned short* __restrict__ w2b, float* __restrict__ out) {
    if (blockIdx.x == (W2B_ELEMS + 255)/256) {
        if (threadIdx.x < 16) out[ZTOT + threadIdx.x] = 0.0f;
        return;
    }
    int idx = blockIdx.x * 256 + threadIdx.x;
    if (idx >= W2B_ELEMS) return;
    int j    = idx & 7;
    int lane = (idx >> 3) & 63;
    int nt   = (idx >> 9) & 7;
    int kidx = idx >> 12;            // 0..17
    int tap  = kidx >> 1;
    int ks   = kidx & 1;
    int ky   = tap / 3;
    int kx   = tap - ky * 3;
    int n    = nt * 16 + (lane & 15);
    int ci   = ks * 32 + (lane >> 4) * 8 + j;
    float v = 0.0f;
    if (n < PPC * CCH) v = W2[((n * HID + ci) * 3 + ky) * 3 + kx];

    // ---- W1 slot? (padding region) ----
    int l15s = lane & 15;
    if (nt == 7 && kidx < 16 && l15s >= 4 && l15s < 12) {
        int f   = kidx >> 1;
        int hi5 = kidx & 1;
        int L   = hi5 * 32 + (lane >> 4) * 8 + (l15s - 4);
        int ks2 = f >> 2;
        int nt1 = f & 3;
        int co  = nt1 * 16 + (L & 15);
        int k   = ks2 * 32 + (L >> 4) * 8 + j;
        v = 0.0f;
        if (k < 36) {
            int tp  = k >> 2;
            int c   = k & 3;
            int ky2 = tp / 3;
            int kx2 = tp - ky2 * 3;
            v = W1[((co * CCH + c) * 3 + ky2) * 3 + kx2];
        }
    }

    w2b[idx] = f2bf(v);
}

__global__ __launch_bounds__(256, 4)
void fused_kernel(const float* __restrict__ x, const float* __restrict__ clean,
                  const float* __restrict__ b1,
                  const float* __restrict__ b2, const unsigned short* __restrict__ w2b,
                  float* __restrict__ out)
{
    // LDS union: one 29952 B region serves all three phase-local buffers.
    //   [0, 25920)      s_hid   (180*HSTR bf16)   live: Phase B write -> Phase C reads
    //   [25920, 27840)  s_cl    (960 bf16)        live: Phase A write -> Phase B reads
    //   [0, 29952)      p_buf   (64*PSTR f32)     live: epilogue only
    // All aliasing is barrier-ordered. Regs bind occupancy at 4 wg/CU (R5).
    __shared__ __align__(16) float s_all[64 * PSTR];       // 29952 B
    __shared__ float s_red[4];

    unsigned short* s_hid = (unsigned short*)s_all;                 // 12960 shorts
    unsigned short* s_cl  = (unsigned short*)s_all + 12960;         // 960 shorts (8B-aligned)

    const int tid  = threadIdx.x;
    const int blk  = blockIdx.x;
    const int b    = blk >> 9;
    const int ty   = (blk >> 4) & 31;
    const int tx   = blk & 15;
    const int Y0 = ty * TH, X0 = tx * TWD;

    const int w    = tid >> 6;        // wave id == spline channel c
    const int lane = tid & 63;
    const int l15  = lane & 15;
    const int quad = lane >> 4;
    const int wy   = w & 1;           // M half: mtiles wy*4 .. wy*4+3 (pixel rows)
    const int wx   = w >> 1;          // N half: ntiles wx*4 .. wx*4+3

    // R14: interior blocks (82%) have every halo coordinate provably in-range
    // (Y0-2>=0, Y0+9<=255, X0-2>=0, X0+17<=255) -> scalar branch skips all
    // bounds logic in Phase A and the Phase-B write.
    const bool interior = (ty >= 1 && ty <= 30 && tx >= 1 && tx <= 14);

    // ---------- Phase A: stage clean tile (12 x 20 x 4ch, zero-padded) as bf16 ----------
    if (interior) {
        for (int i = tid; i < 960; i += 256) {
            int c  = i / 240;
            int r  = i - c * 240;
            int cy = r / 20;
            int cx = r - cy * 20;
            float v = clean[((b*CCH + c) << 16) + (Y0 - 2 + cy)*WW + X0 - 2 + cx];
            s_cl[r * 4 + c] = f2bf(v);
        }
    } else {
        for (int i = tid; i < 960; i += 256) {
            int c  = i / 240;
            int r  = i - c * 240;
            int cy = r / 20;
            int cx = r - cy * 20;
            int iy = Y0 - 2 + cy, ix = X0 - 2 + cx;
            float v = 0.0f;
            if (iy >= 0 && iy < HH && ix >= 0 && ix < WW)
                v = clean[((b*CCH + c) << 16) + iy*WW + ix];
            s_cl[r * 4 + c] = f2bf(v);
        }
    }
    __syncthreads();

    // ---------- Phase B: hid = relu(conv1(clean)) via MFMA, pure bf16 ----------
    // M = 180 halo pixels (pad 192 -> 12 mtiles, 3/wave), N = 64 (4 ntiles), K = 36 pad 64.
    {
        const short8v* __restrict__ wv = (const short8v*)w2b;
        const int hi5 = lane >> 5;
        const int mm  = lane & 31;
        const int slotLane = ((mm >> 3) << 4) + 4 + (mm & 7);   // inverse of prepack's L decode

        f32x4 acc1[3][4];
        #pragma unroll
        for (int nt = 0; nt < 4; ++nt) {
            float bv = b1[nt*16 + l15];               // C col = l15 -> co
            #pragma unroll
            for (int mt = 0; mt < 3; ++mt) {
                acc1[mt][nt][0] = bv; acc1[mt][nt][1] = bv;
                acc1[mt][nt][2] = bv; acc1[mt][nt][3] = bv;
            }
        }
        // Per-lane tap offsets: quad q covers taps {2q,2q+1} (ks=0) and tap 8 (ks=1; k>=36 zeroed in B).
        int t0 = quad * 2, t1 = quad * 2 + 1;
        int ky0 = t0 / 3, kx0 = t0 - ky0 * 3;
        int ky1 = t1 / 3, kx1 = t1 - ky1 * 3;
        const int o0 = (ky0 * 20 + kx0) * 4;
        const int o1 = (ky1 * 20 + kx1) * 4;
        const int o8 = (2 * 20 + 2) * 4;              // tap 8 -> (ky,kx)=(2,2)

        // R14: ks-invariant A-row base hoisted (3 fewer /18 per thread)
        int baseM[3];
        #pragma unroll
        for (int mt = 0; mt < 3; ++mt) {
            int p  = (w*3 + mt)*16 + l15;
            int pc = p > HALO_PIX-1 ? HALO_PIX-1 : p;   // clamp pad rows (results discarded)
            int hy = pc / 18, hx = pc - hy * 18;
            baseM[mt] = (hy * 20 + hx) * 4;
        }

        #pragma unroll
        for (int ks = 0; ks < 2; ++ks) {
            const int oA = ks ? o8 : o0;
            const int oB = ks ? o8 : o1;
            short8v ah[3];
            #pragma unroll
            for (int mt = 0; mt < 3; ++mt) {
                short4v h0 = *(const short4v*)(s_cl + baseM[mt] + oA);
                short4v h1 = *(const short4v*)(s_cl + baseM[mt] + oB);
                ah[mt] = __builtin_shufflevector(h0, h1, 0,1,2,3,4,5,6,7);
            }
            #pragma unroll
            for (int nt = 0; nt < 4; ++nt) {
                int i8 = (((ks*4 + nt)*2 + hi5)*8 + 7)*64 + slotLane;  // (kidx, nt=7, slotLane)
                short8v bh = wv[i8];
                #pragma unroll
                for (int mt = 0; mt < 3; ++mt)
                    acc1[mt][nt] = __builtin_amdgcn_mfma_f32_16x16x32_bf16(ah[mt], bh, acc1[mt][nt], 0,0,0);
            }
        }
        // Write s_hid bf16. Out-of-image halo pixels must be ZERO (conv2 SAME padding).
        if (interior) {
            #pragma unroll
            for (int mt = 0; mt < 3; ++mt) {
                #pragma unroll
                for (int r = 0; r < 4; ++r) {
                    int p = (w*3 + mt)*16 + quad*4 + r;    // C row = quad*4 + reg
                    if (p < HALO_PIX) {
                        #pragma unroll
                        for (int nt = 0; nt < 4; ++nt) {
                            float v = fmaxf(acc1[mt][nt][r], 0.0f);
                            s_hid[p*HSTR + nt*16 + l15] = f2bf(v);
                        }
                    }
                }
            }
        } else {
            #pragma unroll
            for (int mt = 0; mt < 3; ++mt) {
                #pragma unroll
                for (int r = 0; r < 4; ++r) {
                    int p = (w*3 + mt)*16 + quad*4 + r;    // C row = quad*4 + reg
                    if (p < HALO_PIX) {
                        int hy = p / 18, hx = p - hy * 18;
                        int iy = Y0 - 1 + hy, ix = X0 - 1 + hx;
                        bool valid = (iy >= 0 && iy < HH && ix >= 0 && ix < WW);
                        #pragma unroll
                        for (int nt = 0; nt < 4; ++nt) {
                            float v = valid ? fmaxf(acc1[mt][nt][r], 0.0f) : 0.0f;
                            s_hid[p*HSTR + nt*16 + l15] = f2bf(v);
                        }
                    }
                }
            }
        }
    }
    __syncthreads();

    // ---------- x prefetch: both chunks' inputs issued before Phase C ----------
    const int gbase = ((b*CCH + w) << 16) + (Y0 + quad)*WW + X0 + l15;
    float xv0 = x[gbase];
    float xv1 = x[gbase + 4*WW];

    // ---------- Phase C: conv2 as implicit GEMM via MFMA 16x16x32 (W2_hi) ----------
    // Wave (wy,wx): 4 mtiles x 4 ntiles = 16 acc tiles (64 f32/thread) -> 16
    // independent MFMA chains. 288 MFMA/wave. Tap loop fully unrolled (R12).
    f32x4 acc[4][4];
    #pragma unroll
    for (int mi = 0; mi < 4; ++mi)
        #pragma unroll
        for (int t = 0; t < 4; ++t) {
            acc[mi][t][0] = 0.f; acc[mi][t][1] = 0.f;
            acc[mi][t][2] = 0.f; acc[mi][t][3] = 0.f;
        }

    const short8v* __restrict__ wbv_hi = (const short8v*)w2b;
    // A addr (shorts): ((wy*4+mi+ky)*18 + l15+kx)*HSTR + quad*8 + ks*32  (16B-aligned -> b128)
    const int abase = (wy*4) * (18*HSTR) + l15*HSTR + quad*8;

    #pragma unroll
    for (int tap = 0; tap < 9; ++tap) {
        const int ky = tap / 3;              // compile-time
        const int kx = tap - ky * 3;
        const int roff = ky*(18*HSTR) + kx*HSTR;
        #pragma unroll
        for (int ks = 0; ks < 2; ++ks) {
            int boff = ((tap*2 + ks)*8 + wx*4)*64 + lane;
            short8v afr[4];
            #pragma unroll
            for (int mi = 0; mi < 4; ++mi)
                afr[mi] = *(const short8v*)(s_hid + abase + roff + mi*(18*HSTR) + ks*32);
            short8v bfr[4];
            #pragma unroll
            for (int t = 0; t < 4; ++t)
                bfr[t] = wbv_hi[boff + t*64];
            __builtin_amdgcn_s_setprio(1);
            #pragma unroll
            for (int mi = 0; mi < 4; ++mi)
                #pragma unroll
                for (int t = 0; t < 4; ++t)
                    acc[mi][t] = __builtin_amdgcn_mfma_f32_16x16x32_bf16(
                        afr[mi], bfr[t], acc[mi][t], 0, 0, 0);
            __builtin_amdgcn_s_setprio(0);
        }
    }

    // ---------- Epilogue: 2 chunks of 64 pixels through LDS p_buf, then spline ----------
    // R5: cumsum+bin-search+select fused; 2 softplus only. R8: no max-subtract.
    // R12: exp2f folded-constant softmax; lad in log2 domain, scaled once.
    // R14: precise divisions -> v_rcp_f32 (<=1 ulp) via __builtin_amdgcn_rcpf
    // (rib shared by idl/th); log2(dnum)-2*log2(den) -> log2(dnum*rden^2).
    float* p_buf = s_all;
    const float* b2c = b2 + w * PPC;      // wave-uniform -> scalar loads
    float lad2 = 0.0f;                    // log2-domain accumulator
    const float C2 = 0.18033688011112042f;   // 0.125 * log2(e)

    for (int chunk = 0; chunk < 2; ++chunk) {
        __syncthreads();   // chunk 0: all s_hid/s_cl reads done; chunk 1: chunk-0 spline reads done
        if (wy == chunk) {
            #pragma unroll
            for (int mi = 0; mi < 4; ++mi) {
                #pragma unroll
                for (int t = 0; t < 4; ++t) {
                    int col = (wx*4 + t)*16 + l15;
                    if (col < NCOLS) {    // cols >=116 are padding; would wrap PSTR
                        f32x4 v = acc[mi][t];
                        int base = (mi*16 + quad*4) * PSTR + col;
                        p_buf[base]          = v[0];
                        p_buf[base + PSTR]   = v[1];
                        p_buf[base + 2*PSTR] = v[2];
                        p_buf[base + 3*PSTR] = v[3];
                    }
                }
            }
        }
        __syncthreads();

        // spline: thread -> (c = w, chunk-local pixel = lane)
        float xv  = chunk ? xv1 : xv0;    // prefetched before Phase C
        float xin = fminf(fmaxf(xv, -TB), TB);
        int gidx  = gbase + chunk*4*WW;

        const int pbase = lane * PSTR + w * PPC;

        // ---- widths softmax (no max-subtract); cumsum fused with bin locate ----
        float uw[NB];
        float sw = 0.0f;
        #pragma unroll
        for (int j = 0; j < NB; ++j) {
            uw[j] = exp2f((p_buf[pbase + j] + b2c[j]) * C2);
            sw += uw[j];
        }
        float isw = __builtin_amdgcn_rcpf(sw);

        // last j with xin >= cw[j] gives idx (xin >= -TB always -> j=0 triggers)
        float icw = -TB, inw = TB;
        int idx = 0;
        float run = 0.0f;
        float cprev = -TB;
        #pragma unroll
        for (int j = 0; j < NB; ++j) {
            float wj = MINW + (1.0f - MINW*NB) * (uw[j] * isw);
            run += wj;
            float cnext = (j == NB-1) ? TB : (-TB + 2.0f*TB*run);   // cw[j+1]
            bool m = (xin >= cprev);
            icw = m ? cprev : icw;
            inw = m ? cnext : inw;
            idx = m ? j     : idx;
            cprev = cnext;
        }

        // ---- heights softmax (no max-subtract), ich/inh selected during cumsum ----
        float uh[NB];
        float sh = 0.0f;
        #pragma unroll
        for (int j = 0; j < NB; ++j) {
            uh[j] = exp2f((p_buf[pbase + NB + j] + b2c[NB + j]) * C2);
            sh += uh[j];
        }
        float ish = __builtin_amdgcn_rcpf(sh);
        float ich = -TB, inh = -TB;
        float runh = 0.0f;
        #pragma unroll
        for (int j = 0; j < NB; ++j) {
            float c0 = -TB + 2.0f*TB*runh;            // chh[j]
            float hj = MINH + (1.0f - MINH*NB) * (uh[j] * ish);
            runh += hj;
            float c1 = (j == NB-1) ? TB : (-TB + 2.0f*TB*runh);  // chh[j+1]
            bool m = (idx == j);
            ich = m ? c0 : ich;
            inh = m ? c1 : inh;
        }

        // ---- derivatives: only d0 = dv[idx], d1 = dv[idx+1] (2 softplus, not 9) ----
        int k0c = idx - 1; k0c = k0c < 0 ? 0 : k0c;
        int k1c = idx > NB-2 ? NB-2 : idx;
        float u0 = p_buf[pbase + 2*NB + k0c] + b2c[2*NB + k0c];
        float u1 = p_buf[pbase + 2*NB + k1c] + b2c[2*NB + k1c];
        float sp0 = fmaxf(u0, 0.0f) + __logf(1.0f + __expf(-fabsf(u0)));
        float sp1 = fmaxf(u1, 0.0f) + __logf(1.0f + __expf(-fabsf(u1)));
        float d0 = (idx == 0)    ? 1.0f : (MIND + sp0);
        float d1 = (idx == NB-1) ? 1.0f : (MIND + sp1);

        float ibw = inw - icw;
        float ihh = inh - ich;
        float rib = __builtin_amdgcn_rcpf(ibw);
        float idl = ihh * rib;
        float th  = (xin - icw) * rib;
        float omt = 1.0f - th;
        float tt  = th * omt;
        float numer = ihh * (idl*th*th + d0*tt);
        float den   = idl + (d0 + d1 - 2.0f*idl)*tt;
        float rden  = __builtin_amdgcn_rcpf(den);
        float z_in  = ich + numer*rden;
        float dnum  = idl*idl*(d1*th*th + 2.0f*idl*tt + d0*omt*omt);
        float lad_in2 = log2f(dnum * rden * rden);   // log2(dnum) - 2*log2(den)
        bool inside = (xv >= -TB) && (xv <= TB);
        float z = inside ? z_in : xv;
        if (inside) lad2 += lad_in2;
        out[gidx] = z;
    }

    // ---------- block-reduce lad (scale log2->ln once), one atomic per block ----------
    float lad = lad2 * 0.6931471805599453f;
    #pragma unroll
    for (int off = 32; off >= 1; off >>= 1)
        lad += __shfl_xor(lad, off, 64);
    if (lane == 0) s_red[w] = lad;
    __syncthreads();
    if (tid == 0)
        atomicAdd(out + ZTOT + b, s_red[0] + s_red[1] + s_red[2] + s_red[3]);
}

extern "C" void kernel_launch(void* const* d_in, const int* in_sizes, int n_in,
                              void* d_out, int out_size, void* d_ws, size_t ws_size,
                              hipStream_t stream) {
    const float* x     = (const float*)d_in[0];
    const float* clean = (const float*)d_in[1];
    const float* W1    = (const float*)d_in[2];
    const float* b1    = (const float*)d_in[3];
    const float* W2    = (const float*)d_in[4];
    const float* b2    = (const float*)d_in[5];
    float* out = (float*)d_out;
    unsigned short* w2b = (unsigned short*)d_ws;   // 147456 B (hi copy only)

    // zero_lad folded into prepack (extra block) -> 2 launches.
    prepack_w2<<<(W2B_ELEMS + 255)/256 + 1, 256, 0, stream>>>(W2, W1, w2b, out);
    fused_kernel<<<BB*32*16, 256, 0, stream>>>(x, clean, b1, b2, w2b, out);
}